// Round 7
// baseline (59.592 us; speedup 1.0000x reference)
//
#include <hip/hip_runtime.h>
#include <math.h>

typedef _Float16 f16;
typedef _Float16 f16x8 __attribute__((ext_vector_type(8)));
typedef float f32x4 __attribute__((ext_vector_type(4)));

#define NB 8192
#define LOGN (NB * 32)

// ---- ws byte layout (weights only) ----
#define OFF_W0   0              // 4096 f32 (= g0 * sign(v0))
#define OFF_SC1  16384          // 4096 f32 scales for v1 rows
#define OFF_SC2  32768          // 2048 f32
#define OFF_SC3  40960          // 2048 f32
#define OFF_B1   49152          // 262144 f16 fragments [f][ks2][nt4][lane64][8]
#define OFF_B2   573440         // 131072 f16 [f][ks2][nt2][lane][8]
#define OFF_B3   835584         // 65536 f16 [f][nt2][lane][8]

// ---------------- prep 1: norms/scales ----------------
__global__ __launch_bounds__(256)
void prep_norm(const float* __restrict__ v0, const float* __restrict__ g0,
               const float* __restrict__ v1, const float* __restrict__ g1,
               const float* __restrict__ v2, const float* __restrict__ g2,
               const float* __restrict__ v3, const float* __restrict__ g3,
               float* __restrict__ ws) {
    int t = blockIdx.x * blockDim.x + threadIdx.x;
    if (t < 4096) {
        float v = v0[t];
        ws[OFF_W0 / 4 + t] = g0[t] * (v >= 0.f ? 1.f : -1.f);
    } else if (t < 8192) {
        int r = t - 4096;
        const float* vp = v1 + (size_t)r * 64;
        float ss = 0.f;
        #pragma unroll
        for (int i = 0; i < 16; ++i) {
            float4 x = *(const float4*)(vp + i * 4);
            ss += x.x * x.x + x.y * x.y + x.z * x.z + x.w * x.w;
        }
        ws[OFF_SC1 / 4 + r] = g1[r] * __frsqrt_rn(ss);
    } else if (t < 10240) {
        int r = t - 8192;
        const float* vp = v2 + (size_t)r * 64;
        float ss = 0.f;
        #pragma unroll
        for (int i = 0; i < 16; ++i) {
            float4 x = *(const float4*)(vp + i * 4);
            ss += x.x * x.x + x.y * x.y + x.z * x.z + x.w * x.w;
        }
        ws[OFF_SC2 / 4 + r] = g2[r] * __frsqrt_rn(ss);
    } else if (t < 12288) {
        int r = t - 10240;
        const float* vp = v3 + (size_t)r * 32;
        float ss = 0.f;
        #pragma unroll
        for (int i = 0; i < 8; ++i) {
            float4 x = *(const float4*)(vp + i * 4);
            ss += x.x * x.x + x.y * x.y + x.z * x.z + x.w * x.w;
        }
        ws[OFF_SC3 / 4 + r] = g3[r] * __frsqrt_rn(ss);
    }
}

// ---------------- prep 2: scatter weight-normed fp16 fragments ----------------
__global__ __launch_bounds__(256)
void prep_frag(const float* __restrict__ v1, const float* __restrict__ v2,
               const float* __restrict__ v3, const float* __restrict__ ws,
               f16* __restrict__ b1f, f16* __restrict__ b2f, f16* __restrict__ b3f) {
    int t = blockIdx.x * blockDim.x + threadIdx.x;   // 458752 total
    if (t < 262144) {
        int i = t & 7, lane = (t >> 3) & 63, nt = (t >> 9) & 3, ks = (t >> 11) & 1, f = t >> 12;
        int k = ks * 32 + ((lane >> 4) << 3) + i;
        int n = nt * 16 + (lane & 15);
        int r = f * 64 + n;
        b1f[t] = (f16)(v1[(size_t)r * 64 + k] * ws[OFF_SC1 / 4 + r]);
    } else if (t < 393216) {
        int t2 = t - 262144;
        int i = t2 & 7, lane = (t2 >> 3) & 63, nt = (t2 >> 9) & 1, ks = (t2 >> 10) & 1, f = t2 >> 11;
        int k = ks * 32 + ((lane >> 4) << 3) + i;
        int n = nt * 16 + (lane & 15);
        int r = f * 32 + n;
        b2f[t2] = (f16)(v2[(size_t)r * 64 + k] * ws[OFF_SC2 / 4 + r]);
    } else {
        int t3 = t - 393216;
        int i = t3 & 7, lane = (t3 >> 3) & 63, nt = (t3 >> 9) & 1, f = t3 >> 10;
        int k = ((lane >> 4) << 3) + i;
        int n = nt * 16 + (lane & 15);
        int r = f * 32 + n;
        b3f[t3] = (f16)(v3[(size_t)r * 32 + k] * ws[OFF_SC3 / 4 + r]);
    }
}

// ---------------- fused: real MLPs + cat + logits ----------------
// grid 512 blocks x 512 thr (8 waves). Block owns 16 rows; wave w handles
// features [w*8, w*8+8) for all 16 rows. LDS 32,960 B -> 2 blocks/CU =
// 16 waves/CU = 4 waves/SIMD. Logits reduced block-locally.
__global__ __launch_bounds__(512, 4)
void nam_fused(const float* __restrict__ tab, const float* __restrict__ w0,
               const f16* __restrict__ b1f, const f16* __restrict__ b2f,
               const f16* __restrict__ b3f,
               const float* __restrict__ b0, const float* __restrict__ b1,
               const float* __restrict__ b2, const float* __restrict__ memb,
               const float* __restrict__ cat_linear, const float* __restrict__ bias,
               float* __restrict__ feat, float* __restrict__ logits) {
    __shared__ char h1s[8][2048];        // per-wave h1: 16 rows x 128B, XOR-swizzled
    __shared__ char h2s[8][1024];        // per-wave h2: 16 rows x 64B, XOR-swizzled
    __shared__ f16 tv[16][98];           // values  cols 0..95 (pitch 98 = odd dwords)
    __shared__ f16 tm[16][98];           // missing cols 0..95
    __shared__ float lsum[16][33];       // per-(row,o) real-feature logits partials

    const int wave = threadIdx.x >> 6, lane = threadIdx.x & 63;
    const int lq = lane >> 4, lr = lane & 15;
    const int rowbase = blockIdx.x * 16;
    const int f0 = wave * 8;
    char* h1b = h1s[wave];
    char* h2b = h2s[wave];

    // ---- zero lsum (FULL coverage this time: 528 entries, 512 threads) ----
    for (int i = threadIdx.x; i < 16 * 33; i += 512)
        (&lsum[0][0])[i] = 0.f;

    // ---- stage tab rows [rowbase, +16): 48 float4 per row, 768 total ----
    for (int g = threadIdx.x; g < 768; g += 512) {
        int row = g / 48, q = g - row * 48;
        float4 x = *(const float4*)(tab + (size_t)(rowbase + row) * 192 + q * 4);
        int c = q * 4;
        if (c < 96) {
            tv[row][c + 0] = (f16)x.x; tv[row][c + 1] = (f16)x.y;
            tv[row][c + 2] = (f16)x.z; tv[row][c + 3] = (f16)x.w;
        } else {
            int cm = c - 96;
            tm[row][cm + 0] = (f16)x.x; tm[row][cm + 1] = (f16)x.y;
            tm[row][cm + 2] = (f16)x.z; tm[row][cm + 3] = (f16)x.w;
        }
    }
    __syncthreads();

    // lacc[nt][j]: logits contribution for (row = lr, o = nt*16+lq*4+j)
    float lacc[2][4];
    #pragma unroll
    for (int nt = 0; nt < 2; ++nt)
        #pragma unroll
        for (int j = 0; j < 4; ++j) lacc[nt][j] = 0.f;

    #pragma unroll 1
    for (int fi = 0; fi < 8; ++fi) {
        const int f = f0 + fi;

        // ---- B fragments (coalesced 16B/lane, L2-resident) ----
        f16x8 B1[2][4], B2[2][2], B3[2];
        {
            const f16* p1 = b1f + f * 4096 + lane * 8;
            #pragma unroll
            for (int ks = 0; ks < 2; ++ks)
                #pragma unroll
                for (int nt = 0; nt < 4; ++nt)
                    B1[ks][nt] = *(const f16x8*)(p1 + ks * 2048 + nt * 512);
            const f16* p2 = b2f + f * 2048 + lane * 8;
            #pragma unroll
            for (int ks = 0; ks < 2; ++ks)
                #pragma unroll
                for (int nt = 0; nt < 2; ++nt)
                    B2[ks][nt] = *(const f16x8*)(p2 + ks * 1024 + nt * 512);
            const f16* p3 = b3f + f * 1024 + lane * 8;
            #pragma unroll
            for (int nt = 0; nt < 2; ++nt)
                B3[nt] = *(const f16x8*)(p3 + nt * 512);
        }

        // ---- biases / per-row inputs ----
        float b1v[4], b2v[2];
        #pragma unroll
        for (int nt = 0; nt < 4; ++nt) b1v[nt] = b1[f * 64 + nt * 16 + lr];
        #pragma unroll
        for (int nt = 0; nt < 2; ++nt) b2v[nt] = b2[f * 32 + nt * 16 + lr];
        const float vmt = (float)tv[lr][f];
        const float msr = (float)tm[lr][f];

        // ---- layer 0: build A fragment (w0 = +/- g0) ----
        f16x8 A0[2];
        #pragma unroll
        for (int ks = 0; ks < 2; ++ks) {
            float w0v[8], b0v[8];
            *(float4*)&w0v[0] = *(const float4*)(w0 + f * 64 + ks * 32 + lq * 8);
            *(float4*)&w0v[4] = *(const float4*)(w0 + f * 64 + ks * 32 + lq * 8 + 4);
            *(float4*)&b0v[0] = *(const float4*)(b0 + f * 64 + ks * 32 + lq * 8);
            *(float4*)&b0v[4] = *(const float4*)(b0 + f * 64 + ks * 32 + lq * 8 + 4);
            #pragma unroll
            for (int i = 0; i < 8; ++i)
                A0[ks][i] = (f16)fmaxf(fmaf(vmt, w0v[i], b0v[i]), 0.f);
        }

        // ---- layer 1: [16x64] = A0 * W1^T ----
        f32x4 acc1[4];
        #pragma unroll
        for (int nt = 0; nt < 4; ++nt) acc1[nt] = (f32x4){0.f, 0.f, 0.f, 0.f};
        #pragma unroll
        for (int ks = 0; ks < 2; ++ks)
            #pragma unroll
            for (int nt = 0; nt < 4; ++nt)
                acc1[nt] = __builtin_amdgcn_mfma_f32_16x16x32_f16(A0[ks], B1[ks][nt], acc1[nt], 0, 0, 0);
        // relu+bias -> fp16 -> swizzled LDS (h1: pitch 128B, swz (row&7)<<4)
        #pragma unroll
        for (int nt = 0; nt < 4; ++nt) {
            int n = nt * 16 + lr;
            int colb = ((n >> 3) << 4) + ((n & 7) << 1);
            #pragma unroll
            for (int j = 0; j < 4; ++j) {
                int row = lq * 4 + j;
                int byte = ((row << 7) + colb) ^ ((row & 7) << 4);
                *(f16*)(h1b + byte) = (f16)fmaxf(acc1[nt][j] + b1v[nt], 0.f);
            }
        }

        // ---- layer 2: [16x32] = H1 * W2^T ----
        f16x8 A1[2];
        #pragma unroll
        for (int ks = 0; ks < 2; ++ks) {
            int byte = ((lr << 7) + ((ks * 4 + lq) << 4)) ^ ((lr & 7) << 4);
            A1[ks] = *(const f16x8*)(h1b + byte);
        }
        f32x4 acc2[2];
        #pragma unroll
        for (int nt = 0; nt < 2; ++nt) acc2[nt] = (f32x4){0.f, 0.f, 0.f, 0.f};
        #pragma unroll
        for (int ks = 0; ks < 2; ++ks)
            #pragma unroll
            for (int nt = 0; nt < 2; ++nt)
                acc2[nt] = __builtin_amdgcn_mfma_f32_16x16x32_f16(A1[ks], B2[ks][nt], acc2[nt], 0, 0, 0);
        // relu+bias -> fp16 -> swizzled LDS (h2: pitch 64B, swz (row&3)<<4)
        #pragma unroll
        for (int nt = 0; nt < 2; ++nt) {
            int n = nt * 16 + lr;
            int colb = ((n >> 3) << 4) + ((n & 7) << 1);
            #pragma unroll
            for (int j = 0; j < 4; ++j) {
                int row = lq * 4 + j;
                int byte = ((row << 6) + colb) ^ ((row & 3) << 4);
                *(f16*)(h2b + byte) = (f16)fmaxf(acc2[nt][j] + b2v[nt], 0.f);
            }
        }

        // ---- layer 3 TRANSPOSED: D[o][brow] = W3 * H2^T -> float4 stores ----
        f16x8 A2;
        {
            int byte = ((lr << 6) + (lq << 4)) ^ ((lr & 3) << 4);
            A2 = *(const f16x8*)(h2b + byte);
        }
        f32x4 accT[2];
        #pragma unroll
        for (int nt = 0; nt < 2; ++nt) accT[nt] = (f32x4){0.f, 0.f, 0.f, 0.f};
        #pragma unroll
        for (int nt = 0; nt < 2; ++nt)
            accT[nt] = __builtin_amdgcn_mfma_f32_16x16x32_f16(B3[nt], A2, accT[nt], 0, 0, 0);

        // ---- epilogue: mask (per-lane row), missing-emb, float4 store ----
        const bool hasemb = (f < 16);
        float4 e[2] = {{0, 0, 0, 0}, {0, 0, 0, 0}};
        if (hasemb) {
            #pragma unroll
            for (int nt = 0; nt < 2; ++nt)
                e[nt] = *(const float4*)(memb + (8 + f) * 32 + nt * 16 + lq * 4);
        }
        {
            const int row = rowbase + lr;
            const float m = msr;
            const float keep = 1.f - m;
            float* dst = feat + (size_t)row * 3072 + f * 32 + lq * 4;
            #pragma unroll
            for (int nt = 0; nt < 2; ++nt) {
                float4 v;
                v.x = accT[nt][0] * keep;
                v.y = accT[nt][1] * keep;
                v.z = accT[nt][2] * keep;
                v.w = accT[nt][3] * keep;
                if (hasemb) {
                    v.x = fmaf(e[nt].x, m, v.x);
                    v.y = fmaf(e[nt].y, m, v.y);
                    v.z = fmaf(e[nt].z, m, v.z);
                    v.w = fmaf(e[nt].w, m, v.w);
                }
                *(float4*)(dst + nt * 16) = v;
                lacc[nt][0] += v.x;
                lacc[nt][1] += v.y;
                lacc[nt][2] += v.z;
                lacc[nt][3] += v.w;
            }
        }
    }

    // ---- reduce real logits across the 8 waves (LDS atomics, block-local) ----
    #pragma unroll
    for (int nt = 0; nt < 2; ++nt)
        #pragma unroll
        for (int j = 0; j < 4; ++j)
            atomicAdd(&lsum[lr][nt * 16 + lq * 4 + j], lacc[nt][j]);
    __syncthreads();

    // ---- tail: cat features + final logits (thread = (row, o), 512 exact) ----
    {
        const int row = threadIdx.x >> 5;            // 0..15
        const int o = threadIdx.x & 31;              // 0..31
        const int grow = rowbase + row;
        float s = bias[o] + lsum[row][o];
        float* fb = feat + (size_t)grow * 3072 + 64 * 32 + o;
        #pragma unroll
        for (int fc = 0; fc < 32; ++fc) {
            float val = (float)tv[row][64 + fc];
            float m   = (float)tm[row][64 + fc];
            float r = cat_linear[fc * 32 + o] * val * (1.f - m);
            if (fc < 8) r = fmaf(memb[fc * 32 + o], m, r);
            fb[fc * 32] = r;
            s += r;
        }
        logits[(size_t)grow * 32 + o] = s;
    }
}

extern "C" void kernel_launch(void* const* d_in, const int* in_sizes, int n_in,
                              void* d_out, int out_size, void* d_ws, size_t ws_size,
                              hipStream_t stream) {
    const float* tab        = (const float*)d_in[0];
    const float* v0         = (const float*)d_in[1];
    const float* g0         = (const float*)d_in[2];
    const float* b0         = (const float*)d_in[3];
    const float* v1         = (const float*)d_in[4];
    const float* g1         = (const float*)d_in[5];
    const float* b1         = (const float*)d_in[6];
    const float* v2         = (const float*)d_in[7];
    const float* g2         = (const float*)d_in[8];
    const float* b2         = (const float*)d_in[9];
    const float* v3         = (const float*)d_in[10];
    const float* g3         = (const float*)d_in[11];
    const float* cat_linear = (const float*)d_in[12];
    const float* memb       = (const float*)d_in[13];
    const float* bias       = (const float*)d_in[14];

    float* out    = (float*)d_out;
    float* logits = out;                 // [8192][32]
    float* feat   = out + LOGN;          // [8192][96][32]

    float* ws   = (float*)d_ws;
    float* w0   = (float*)((char*)d_ws + OFF_W0);
    f16*   b1f  = (f16*)((char*)d_ws + OFF_B1);
    f16*   b2f  = (f16*)((char*)d_ws + OFF_B2);
    f16*   b3f  = (f16*)((char*)d_ws + OFF_B3);

    prep_norm<<<48, 256, 0, stream>>>(v0, g0, v1, g1, v2, g2, v3, g3, ws);
    prep_frag<<<1792, 256, 0, stream>>>(v1, v2, v3, ws, b1f, b2f, b3f);

    nam_fused<<<512, 512, 0, stream>>>(tab, w0, b1f, b2f, b3f, b0, b1, b2,
                                       memb, cat_linear, bias, feat, logits);
}

// Round 8
// 50.442 us; speedup vs baseline: 1.1814x; 1.1814x over previous
//
#include <hip/hip_runtime.h>
#include <math.h>

typedef _Float16 f16;
typedef _Float16 f16x8 __attribute__((ext_vector_type(8)));
typedef float f32x4 __attribute__((ext_vector_type(4)));

#define NB 8192
#define LOGN (NB * 32)

// ---- ws byte layout ----
#define OFF_W0   0              // 4096 f32 (= g0 * sign(v0))
#define OFF_B1   16384          // 262144 f16 fragments [f][ks2][nt4][lane64][8]
#define OFF_B2   540672         // 131072 f16 [f][ks2][nt2][lane][8]
#define OFF_B3   802816         // 65536 f16 [f][nt2][lane][8]
#define OFF_PART 933888         // 8 planes of [8192][32] f32 partial logits
#define WS_NEED  (OFF_PART + 8ull * LOGN * 4ull)

// ---------------- prep (merged): weight-norm -> w0 + fp16 MFMA fragments ----------------
// 462848 threads. 8-lane groups share one weight row; ssq via shfl_xor butterfly.
__global__ __launch_bounds__(256)
void prep_all(const float* __restrict__ v0, const float* __restrict__ g0,
              const float* __restrict__ v1, const float* __restrict__ g1,
              const float* __restrict__ v2, const float* __restrict__ g2,
              const float* __restrict__ v3, const float* __restrict__ g3,
              float* __restrict__ w0, f16* __restrict__ b1f,
              f16* __restrict__ b2f, f16* __restrict__ b3f) {
    int t = blockIdx.x * 256 + threadIdx.x;
    if (t < 4096) {
        float v = v0[t];
        w0[t] = g0[t] * (v >= 0.f ? 1.f : -1.f);
        return;
    }
    int u = t - 4096;
    if (u < 262144) {
        // b1f[u]: u = f*4096 + ks*2048 + nt*512 + lane*8 + i
        int i = u & 7, lane = (u >> 3) & 63, nt = (u >> 9) & 3, ks = (u >> 11) & 1, f = u >> 12;
        int r = f * 64 + nt * 16 + (lane & 15);
        const float* vp = v1 + (size_t)r * 64;
        float4 a = *(const float4*)(vp + i * 8);
        float4 b = *(const float4*)(vp + i * 8 + 4);
        float ss = a.x * a.x + a.y * a.y + a.z * a.z + a.w * a.w
                 + b.x * b.x + b.y * b.y + b.z * b.z + b.w * b.w;
        ss += __shfl_xor(ss, 1); ss += __shfl_xor(ss, 2); ss += __shfl_xor(ss, 4);
        float scale = g1[r] * __frsqrt_rn(ss);
        int k = ks * 32 + ((lane >> 4) << 3) + i;
        b1f[u] = (f16)(vp[k] * scale);
    } else if (u < 393216) {
        int t2 = u - 262144;
        int i = t2 & 7, lane = (t2 >> 3) & 63, nt = (t2 >> 9) & 1, ks = (t2 >> 10) & 1, f = t2 >> 11;
        int r = f * 32 + nt * 16 + (lane & 15);
        const float* vp = v2 + (size_t)r * 64;
        float4 a = *(const float4*)(vp + i * 8);
        float4 b = *(const float4*)(vp + i * 8 + 4);
        float ss = a.x * a.x + a.y * a.y + a.z * a.z + a.w * a.w
                 + b.x * b.x + b.y * b.y + b.z * b.z + b.w * b.w;
        ss += __shfl_xor(ss, 1); ss += __shfl_xor(ss, 2); ss += __shfl_xor(ss, 4);
        float scale = g2[r] * __frsqrt_rn(ss);
        int k = ks * 32 + ((lane >> 4) << 3) + i;
        b2f[t2] = (f16)(vp[k] * scale);
    } else {
        int t3 = u - 393216;
        int i = t3 & 7, lane = (t3 >> 3) & 63, nt = (t3 >> 9) & 1, f = t3 >> 10;
        int r = f * 32 + nt * 16 + (lane & 15);
        const float* vp = v3 + (size_t)r * 32;
        float4 a = *(const float4*)(vp + i * 4);
        float ss = a.x * a.x + a.y * a.y + a.z * a.z + a.w * a.w;
        ss += __shfl_xor(ss, 1); ss += __shfl_xor(ss, 2); ss += __shfl_xor(ss, 4);
        float scale = g3[r] * __frsqrt_rn(ss);
        int k = ((lane >> 4) << 3) + i;
        b3f[t3] = (f16)(vp[k] * scale);
    }
}

// ---------------- real features: MFMA MLP chain (R3 structure + transposed L3) ----------------
// grid (64 batch-tiles, 8 feature-groups) x 256 thr. Wave-private: 32 rows/wave, 8 features.
__global__ __launch_bounds__(256, 2)
void nam_real_mfma(const float* __restrict__ tab, const float* __restrict__ w0,
                   const f16* __restrict__ b1f, const f16* __restrict__ b2f,
                   const f16* __restrict__ b3f,
                   const float* __restrict__ b0, const float* __restrict__ b1,
                   const float* __restrict__ b2, const float* __restrict__ memb,
                   float* __restrict__ feat, float* __restrict__ part) {
    __shared__ char lds[4][8192];           // per-wave h1/h2 staging
    __shared__ float tv[128][8];            // tab values (this block's 8 features)
    __shared__ float tm[128][8];            // tab missing flags
    const int wave = threadIdx.x >> 6, lane = threadIdx.x & 63;
    const int lq = lane >> 4, lr = lane & 15;
    const int rowbase = blockIdx.x * 128 + wave * 32;
    const int f0 = blockIdx.y * 8;
    char* h1b = lds[wave];
    char* h2b = lds[wave] + 4096;

    // ---- coalesced tab staging: 128 rows x (8 val + 8 miss) ----
    #pragma unroll
    for (int it = 0; it < 8; ++it) {
        int g = it * 256 + threadIdx.x;     // 0..2047
        int row = g >> 4, w = g & 15;
        int col = (w < 8) ? (f0 + w) : (96 + f0 + (w - 8));
        float x = tab[(size_t)(blockIdx.x * 128 + row) * 192 + col];
        if (w < 8) tv[row][w] = x; else tm[row][w - 8] = x;
    }
    __syncthreads();

    // lacc[mt][nt][j]: logits contribution for (row = rowbase+mt*16+lr, o = nt*16+lq*4+j)
    float lacc[2][2][4];
    #pragma unroll
    for (int mt = 0; mt < 2; ++mt)
        #pragma unroll
        for (int nt = 0; nt < 2; ++nt)
            #pragma unroll
            for (int j = 0; j < 4; ++j) lacc[mt][nt][j] = 0.f;

    #pragma unroll 1
    for (int fi = 0; fi < 8; ++fi) {
        const int f = f0 + fi;

        // ---- B fragments (coalesced 16B/lane, L2-resident) ----
        f16x8 B1[2][4], B2[2][2], B3[2];
        {
            const f16* p1 = b1f + f * 4096 + lane * 8;
            #pragma unroll
            for (int ks = 0; ks < 2; ++ks)
                #pragma unroll
                for (int nt = 0; nt < 4; ++nt)
                    B1[ks][nt] = *(const f16x8*)(p1 + ks * 2048 + nt * 512);
            const f16* p2 = b2f + f * 2048 + lane * 8;
            #pragma unroll
            for (int ks = 0; ks < 2; ++ks)
                #pragma unroll
                for (int nt = 0; nt < 2; ++nt)
                    B2[ks][nt] = *(const f16x8*)(p2 + ks * 1024 + nt * 512);
            const f16* p3 = b3f + f * 1024 + lane * 8;
            #pragma unroll
            for (int nt = 0; nt < 2; ++nt)
                B3[nt] = *(const f16x8*)(p3 + nt * 512);
        }

        // ---- biases / per-row inputs (from LDS) ----
        float b1v[4], b2v[2];
        #pragma unroll
        for (int nt = 0; nt < 4; ++nt) b1v[nt] = b1[f * 64 + nt * 16 + lr];
        #pragma unroll
        for (int nt = 0; nt < 2; ++nt) b2v[nt] = b2[f * 32 + nt * 16 + lr];
        float vmt[2], msr[2];
        #pragma unroll
        for (int mt = 0; mt < 2; ++mt) {
            vmt[mt] = tv[wave * 32 + mt * 16 + lr][fi];
            msr[mt] = tm[wave * 32 + mt * 16 + lr][fi];   // per-lane row mask (transposed epilogue)
        }

        // ---- layer 0: build A fragments in registers (w0 = +/- g0) ----
        f16x8 A0[2][2];
        #pragma unroll
        for (int ks = 0; ks < 2; ++ks) {
            float w0v[8], b0v[8];
            *(float4*)&w0v[0] = *(const float4*)(w0 + f * 64 + ks * 32 + lq * 8);
            *(float4*)&w0v[4] = *(const float4*)(w0 + f * 64 + ks * 32 + lq * 8 + 4);
            *(float4*)&b0v[0] = *(const float4*)(b0 + f * 64 + ks * 32 + lq * 8);
            *(float4*)&b0v[4] = *(const float4*)(b0 + f * 64 + ks * 32 + lq * 8 + 4);
            #pragma unroll
            for (int mt = 0; mt < 2; ++mt)
                #pragma unroll
                for (int i = 0; i < 8; ++i)
                    A0[mt][ks][i] = (f16)fmaxf(fmaf(vmt[mt], w0v[i], b0v[i]), 0.f);
        }

        // ---- layer 1: [32x64] = A0 * W1^T ----
        f32x4 acc1[2][4];
        #pragma unroll
        for (int mt = 0; mt < 2; ++mt)
            #pragma unroll
            for (int nt = 0; nt < 4; ++nt) acc1[mt][nt] = (f32x4){0.f, 0.f, 0.f, 0.f};
        #pragma unroll
        for (int ks = 0; ks < 2; ++ks)
            #pragma unroll
            for (int nt = 0; nt < 4; ++nt)
                #pragma unroll
                for (int mt = 0; mt < 2; ++mt)
                    acc1[mt][nt] = __builtin_amdgcn_mfma_f32_16x16x32_f16(A0[mt][ks], B1[ks][nt], acc1[mt][nt], 0, 0, 0);
        // relu+bias -> fp16 -> swizzled LDS
        #pragma unroll
        for (int mt = 0; mt < 2; ++mt)
            #pragma unroll
            for (int nt = 0; nt < 4; ++nt) {
                int n = nt * 16 + lr;
                int colb = ((n >> 3) << 4) + ((n & 7) << 1);
                #pragma unroll
                for (int j = 0; j < 4; ++j) {
                    int row = mt * 16 + lq * 4 + j;
                    int byte = ((row << 7) + colb) ^ ((row & 7) << 4);
                    *(f16*)(h1b + byte) = (f16)fmaxf(acc1[mt][nt][j] + b1v[nt], 0.f);
                }
            }

        // ---- layer 2: [32x32] = H1 * W2^T ----
        f16x8 A1[2][2];
        #pragma unroll
        for (int mt = 0; mt < 2; ++mt)
            #pragma unroll
            for (int ks = 0; ks < 2; ++ks) {
                int row = mt * 16 + lr;
                int byte = ((row << 7) + ((ks * 4 + lq) << 4)) ^ ((row & 7) << 4);
                A1[mt][ks] = *(const f16x8*)(h1b + byte);
            }
        f32x4 acc2[2][2];
        #pragma unroll
        for (int mt = 0; mt < 2; ++mt)
            #pragma unroll
            for (int nt = 0; nt < 2; ++nt) acc2[mt][nt] = (f32x4){0.f, 0.f, 0.f, 0.f};
        #pragma unroll
        for (int ks = 0; ks < 2; ++ks)
            #pragma unroll
            for (int nt = 0; nt < 2; ++nt)
                #pragma unroll
                for (int mt = 0; mt < 2; ++mt)
                    acc2[mt][nt] = __builtin_amdgcn_mfma_f32_16x16x32_f16(A1[mt][ks], B2[ks][nt], acc2[mt][nt], 0, 0, 0);
        #pragma unroll
        for (int mt = 0; mt < 2; ++mt)
            #pragma unroll
            for (int nt = 0; nt < 2; ++nt) {
                int n = nt * 16 + lr;
                int colb = ((n >> 3) << 4) + ((n & 7) << 1);
                #pragma unroll
                for (int j = 0; j < 4; ++j) {
                    int row = mt * 16 + lq * 4 + j;
                    int byte = ((row << 7) + colb) ^ ((row & 7) << 4);
                    *(f16*)(h2b + byte) = (f16)fmaxf(acc2[mt][nt][j] + b2v[nt], 0.f);
                }
            }

        // ---- layer 3 TRANSPOSED: D[o][brow] = W3 * H2^T (verified R4) ----
        f16x8 A2[2];
        #pragma unroll
        for (int mt = 0; mt < 2; ++mt) {
            int row = mt * 16 + lr;
            int byte = ((row << 7) + (lq << 4)) ^ ((row & 7) << 4);
            A2[mt] = *(const f16x8*)(h2b + byte);
        }
        f32x4 accT[2][2];
        #pragma unroll
        for (int nt = 0; nt < 2; ++nt)
            #pragma unroll
            for (int mt = 0; mt < 2; ++mt) accT[nt][mt] = (f32x4){0.f, 0.f, 0.f, 0.f};
        #pragma unroll
        for (int nt = 0; nt < 2; ++nt)
            #pragma unroll
            for (int mt = 0; mt < 2; ++mt)
                accT[nt][mt] = __builtin_amdgcn_mfma_f32_16x16x32_f16(B3[nt], A2[mt], accT[nt][mt], 0, 0, 0);

        // ---- epilogue: mask (per-lane row), missing-emb (contiguous o), float4 store ----
        const bool hasemb = (f < 16);
        float4 e[2] = {{0, 0, 0, 0}, {0, 0, 0, 0}};
        if (hasemb) {
            #pragma unroll
            for (int nt = 0; nt < 2; ++nt)
                e[nt] = *(const float4*)(memb + (8 + f) * 32 + nt * 16 + lq * 4);
        }
        #pragma unroll
        for (int mt = 0; mt < 2; ++mt) {
            const int row = rowbase + mt * 16 + lr;
            const float m = msr[mt];
            const float keep = 1.f - m;
            float* dst = feat + (size_t)row * 3072 + f * 32 + lq * 4;
            #pragma unroll
            for (int nt = 0; nt < 2; ++nt) {
                float4 v;
                v.x = accT[nt][mt][0] * keep;
                v.y = accT[nt][mt][1] * keep;
                v.z = accT[nt][mt][2] * keep;
                v.w = accT[nt][mt][3] * keep;
                if (hasemb) {
                    v.x = fmaf(e[nt].x, m, v.x);
                    v.y = fmaf(e[nt].y, m, v.y);
                    v.z = fmaf(e[nt].z, m, v.z);
                    v.w = fmaf(e[nt].w, m, v.w);
                }
                *(float4*)(dst + nt * 16) = v;
                lacc[mt][nt][0] += v.x;
                lacc[mt][nt][1] += v.y;
                lacc[mt][nt][2] += v.z;
                lacc[mt][nt][3] += v.w;
            }
        }
    }

    // ---- partial-plane store (float4, no atomics) ----
    if (part) {
        float* pp = part + (size_t)blockIdx.y * LOGN;
        #pragma unroll
        for (int mt = 0; mt < 2; ++mt) {
            const int row = rowbase + mt * 16 + lr;
            #pragma unroll
            for (int nt = 0; nt < 2; ++nt) {
                float4 v;
                v.x = lacc[mt][nt][0]; v.y = lacc[mt][nt][1];
                v.z = lacc[mt][nt][2]; v.w = lacc[mt][nt][3];
                *(float4*)(pp + (size_t)row * 32 + nt * 16 + lq * 4) = v;
            }
        }
    }
}

// ---------------- categorical features + final logits (fused, vectorized) ----------------
// 65536 threads: thread = (batch row, 4 contiguous outputs)
__global__ __launch_bounds__(256)
void nam_cat_reduce(const float* __restrict__ tab, const float* __restrict__ cat_linear,
                    const float* __restrict__ memb, const float* __restrict__ bias,
                    const float* __restrict__ part, float* __restrict__ feat,
                    float* __restrict__ logits) {
    int t = blockIdx.x * 256 + threadIdx.x;   // 65536
    int o4 = (t & 7) * 4;
    int b = t >> 3;
    const float4* tb4 = (const float4*)(tab + (size_t)b * 192);
    float4 s = *(const float4*)(bias + o4);
    if (part) {
        #pragma unroll
        for (int g = 0; g < 8; ++g) {
            float4 p = *(const float4*)(part + (size_t)g * LOGN + (size_t)b * 32 + o4);
            s.x += p.x; s.y += p.y; s.z += p.z; s.w += p.w;
        }
    }
    float* fb = feat + (size_t)b * 3072 + 64 * 32 + o4;
    #pragma unroll
    for (int q = 0; q < 8; ++q) {
        float4 v4 = tb4[16 + q];     // values cols 64+4q..
        float4 m4 = tb4[40 + q];     // missing cols 160+4q..
        float vv[4] = {v4.x, v4.y, v4.z, v4.w};
        float mm[4] = {m4.x, m4.y, m4.z, m4.w};
        #pragma unroll
        for (int e = 0; e < 4; ++e) {
            int fc = q * 4 + e;
            float vk = vv[e] * (1.f - mm[e]);
            float4 cl4 = *(const float4*)(cat_linear + fc * 32 + o4);
            float4 r;
            r.x = cl4.x * vk; r.y = cl4.y * vk; r.z = cl4.z * vk; r.w = cl4.w * vk;
            if (fc < 8) {
                float4 mb4 = *(const float4*)(memb + fc * 32 + o4);
                r.x = fmaf(mb4.x, mm[e], r.x);
                r.y = fmaf(mb4.y, mm[e], r.y);
                r.z = fmaf(mb4.z, mm[e], r.z);
                r.w = fmaf(mb4.w, mm[e], r.w);
            }
            *(float4*)(fb + fc * 32) = r;
            s.x += r.x; s.y += r.y; s.z += r.z; s.w += r.w;
        }
    }
    if (part) *(float4*)(logits + (size_t)b * 32 + o4) = s;
}

// ---------------- fallback logits (if ws too small for partials) ----------------
__global__ __launch_bounds__(256)
void nam_logits(const float* __restrict__ feat, const float* __restrict__ bias,
                float* __restrict__ logits) {
    int t = blockIdx.x * 256 + threadIdx.x;   // 65536
    int o4 = (t & 7) * 4;
    int b = t >> 3;
    float4 s = *(const float4*)(bias + o4);
    const float* fp = feat + (size_t)b * 3072 + o4;
    #pragma unroll 8
    for (int f = 0; f < 96; ++f) {
        float4 p = *(const float4*)(fp + f * 32);
        s.x += p.x; s.y += p.y; s.z += p.z; s.w += p.w;
    }
    *(float4*)(logits + (size_t)b * 32 + o4) = s;
}

extern "C" void kernel_launch(void* const* d_in, const int* in_sizes, int n_in,
                              void* d_out, int out_size, void* d_ws, size_t ws_size,
                              hipStream_t stream) {
    const float* tab        = (const float*)d_in[0];
    const float* v0         = (const float*)d_in[1];
    const float* g0         = (const float*)d_in[2];
    const float* b0         = (const float*)d_in[3];
    const float* v1         = (const float*)d_in[4];
    const float* g1         = (const float*)d_in[5];
    const float* b1         = (const float*)d_in[6];
    const float* v2         = (const float*)d_in[7];
    const float* g2         = (const float*)d_in[8];
    const float* b2         = (const float*)d_in[9];
    const float* v3         = (const float*)d_in[10];
    const float* g3         = (const float*)d_in[11];
    const float* cat_linear = (const float*)d_in[12];
    const float* memb       = (const float*)d_in[13];
    const float* bias       = (const float*)d_in[14];

    float* out    = (float*)d_out;
    float* logits = out;                 // [8192][32]
    float* feat   = out + LOGN;          // [8192][96][32]

    float* w0   = (float*)((char*)d_ws + OFF_W0);
    f16*   b1f  = (f16*)((char*)d_ws + OFF_B1);
    f16*   b2f  = (f16*)((char*)d_ws + OFF_B2);
    f16*   b3f  = (f16*)((char*)d_ws + OFF_B3);
    float* part = (float*)((char*)d_ws + OFF_PART);
    const bool use_part = ws_size >= WS_NEED;
    float* partp = use_part ? part : nullptr;

    prep_all<<<1808, 256, 0, stream>>>(v0, g0, v1, g1, v2, g2, v3, g3, w0, b1f, b2f, b3f);

    dim3 gr(64, 8);
    nam_real_mfma<<<gr, 256, 0, stream>>>(tab, w0, b1f, b2f, b3f, b0, b1, b2, memb, feat, partp);

    nam_cat_reduce<<<256, 256, 0, stream>>>(tab, cat_linear, memb, bias, partp, feat, logits);

    if (!use_part)
        nam_logits<<<256, 256, 0, stream>>>(feat, bias, logits);
}

// Round 10
// 49.508 us; speedup vs baseline: 1.2037x; 1.0189x over previous
//
#include <hip/hip_runtime.h>
#include <math.h>

typedef _Float16 f16;
typedef __fp16 fp16x2 __attribute__((ext_vector_type(2)));
typedef _Float16 f16x4 __attribute__((ext_vector_type(4)));
typedef _Float16 f16x8 __attribute__((ext_vector_type(8)));
typedef float f32x4 __attribute__((ext_vector_type(4)));

#define NB 8192
#define LOGN (NB * 32)

// ---- ws byte layout ----
#define OFF_W0   0              // 4096 f32 (= g0 * sign(v0))
#define OFF_B1   16384          // 262144 f16 fragments [f][ks2][nt4][lane64][8]
#define OFF_B2   540672         // 131072 f16 [f][ks2][nt2][lane][8]
#define OFF_B3   802816         // 65536 f16 [f][nt2][lane][8]
#define OFF_PART 933888         // 8 planes of [8192][32] f32 partial logits
#define WS_NEED  (OFF_PART + 8ull * LOGN * 4ull)

static __device__ __forceinline__ f16x4 pack4(float a, float b, float c, float d) {
    union { fp16x2 h2[2]; f16x4 h4; } u;
    u.h2[0] = __builtin_amdgcn_cvt_pkrtz(a, b);
    u.h2[1] = __builtin_amdgcn_cvt_pkrtz(c, d);
    return u.h4;
}

// ---------------- prep (merged): weight-norm -> w0 + fp16 MFMA fragments ----------------
__global__ __launch_bounds__(256)
void prep_all(const float* __restrict__ v0, const float* __restrict__ g0,
              const float* __restrict__ v1, const float* __restrict__ g1,
              const float* __restrict__ v2, const float* __restrict__ g2,
              const float* __restrict__ v3, const float* __restrict__ g3,
              float* __restrict__ w0, f16* __restrict__ b1f,
              f16* __restrict__ b2f, f16* __restrict__ b3f) {
    int t = blockIdx.x * 256 + threadIdx.x;
    if (t < 4096) {
        float v = v0[t];
        w0[t] = g0[t] * (v >= 0.f ? 1.f : -1.f);
        return;
    }
    int u = t - 4096;
    if (u < 262144) {
        int i = u & 7, lane = (u >> 3) & 63, nt = (u >> 9) & 3, ks = (u >> 11) & 1, f = u >> 12;
        int r = f * 64 + nt * 16 + (lane & 15);
        const float* vp = v1 + (size_t)r * 64;
        float4 a = *(const float4*)(vp + i * 8);
        float4 b = *(const float4*)(vp + i * 8 + 4);
        float ss = a.x * a.x + a.y * a.y + a.z * a.z + a.w * a.w
                 + b.x * b.x + b.y * b.y + b.z * b.z + b.w * b.w;
        ss += __shfl_xor(ss, 1); ss += __shfl_xor(ss, 2); ss += __shfl_xor(ss, 4);
        float scale = g1[r] * __frsqrt_rn(ss);
        int k = ks * 32 + ((lane >> 4) << 3) + i;
        b1f[u] = (f16)(vp[k] * scale);
    } else if (u < 393216) {
        int t2 = u - 262144;
        int i = t2 & 7, lane = (t2 >> 3) & 63, nt = (t2 >> 9) & 1, ks = (t2 >> 10) & 1, f = t2 >> 11;
        int r = f * 32 + nt * 16 + (lane & 15);
        const float* vp = v2 + (size_t)r * 64;
        float4 a = *(const float4*)(vp + i * 8);
        float4 b = *(const float4*)(vp + i * 8 + 4);
        float ss = a.x * a.x + a.y * a.y + a.z * a.z + a.w * a.w
                 + b.x * b.x + b.y * b.y + b.z * b.z + b.w * b.w;
        ss += __shfl_xor(ss, 1); ss += __shfl_xor(ss, 2); ss += __shfl_xor(ss, 4);
        float scale = g2[r] * __frsqrt_rn(ss);
        int k = ks * 32 + ((lane >> 4) << 3) + i;
        b2f[t2] = (f16)(vp[k] * scale);
    } else {
        int t3 = u - 393216;
        int i = t3 & 7, lane = (t3 >> 3) & 63, nt = (t3 >> 9) & 1, f = t3 >> 10;
        int r = f * 32 + nt * 16 + (lane & 15);
        const float* vp = v3 + (size_t)r * 32;
        float4 a = *(const float4*)(vp + i * 4);
        float ss = a.x * a.x + a.y * a.y + a.z * a.z + a.w * a.w;
        ss += __shfl_xor(ss, 1); ss += __shfl_xor(ss, 2); ss += __shfl_xor(ss, 4);
        float scale = g3[r] * __frsqrt_rn(ss);
        int k = ((lane >> 4) << 3) + i;
        b3f[t3] = (f16)(vp[k] * scale);
    }
}

// ---------------- real features: all-swapped MFMA MLP chain ----------------
// grid (64 batch-tiles, 8 feature-groups) x 256 thr. Wave-private: 32 rows/wave, 8 features.
// All layers compute D^T = mfma(Wfrag, Hfrag): lane holds (batch=lr) x (4 contiguous n)
// -> packed ds_write_b64 everywhere (12 b64 writes + 6 b128 reads /feature vs 48 u16 + 6).
__global__ __launch_bounds__(256, 2)
void nam_real_mfma(const float* __restrict__ tab, const float* __restrict__ w0,
                   const f16* __restrict__ b1f, const f16* __restrict__ b2f,
                   const f16* __restrict__ b3f,
                   const float* __restrict__ b0, const float* __restrict__ b1,
                   const float* __restrict__ b2, const float* __restrict__ memb,
                   float* __restrict__ feat, float* __restrict__ part) {
    __shared__ char lds[4][8192];           // per-wave: h1 [32][128B] + h2 [32][128B], XOR-swizzled
    __shared__ float tv[128][8];            // tab values (this block's 8 features)
    __shared__ float tm[128][8];            // tab missing flags
    const int wave = threadIdx.x >> 6, lane = threadIdx.x & 63;
    const int lq = lane >> 4, lr = lane & 15;
    const int rowbase = blockIdx.x * 128 + wave * 32;
    const int f0 = blockIdx.y * 8;
    char* h1b = lds[wave];
    char* h2b = lds[wave] + 4096;

    // ---- coalesced tab staging: 128 rows x (8 val + 8 miss) ----
    #pragma unroll
    for (int it = 0; it < 8; ++it) {
        int g = it * 256 + threadIdx.x;     // 0..2047
        int row = g >> 4, w = g & 15;
        int col = (w < 8) ? (f0 + w) : (96 + f0 + (w - 8));
        float x = tab[(size_t)(blockIdx.x * 128 + row) * 192 + col];
        if (w < 8) tv[row][w] = x; else tm[row][w - 8] = x;
    }
    __syncthreads();

    // lacc[mt][nt][j]: logits contribution for (row = rowbase+mt*16+lr, o = nt*16+lq*4+j)
    float lacc[2][2][4];
    #pragma unroll
    for (int mt = 0; mt < 2; ++mt)
        #pragma unroll
        for (int nt = 0; nt < 2; ++nt)
            #pragma unroll
            for (int j = 0; j < 4; ++j) lacc[mt][nt][j] = 0.f;

    #pragma unroll 1
    for (int fi = 0; fi < 8; ++fi) {
        const int f = f0 + fi;

        // ---- B fragments (coalesced 16B/lane, L2-resident) ----
        f16x8 B1[2][4], B2[2][2], B3[2];
        {
            const f16* p1 = b1f + f * 4096 + lane * 8;
            #pragma unroll
            for (int ks = 0; ks < 2; ++ks)
                #pragma unroll
                for (int nt = 0; nt < 4; ++nt)
                    B1[ks][nt] = *(const f16x8*)(p1 + ks * 2048 + nt * 512);
            const f16* p2 = b2f + f * 2048 + lane * 8;
            #pragma unroll
            for (int ks = 0; ks < 2; ++ks)
                #pragma unroll
                for (int nt = 0; nt < 2; ++nt)
                    B2[ks][nt] = *(const f16x8*)(p2 + ks * 1024 + nt * 512);
            const f16* p3 = b3f + f * 1024 + lane * 8;
            #pragma unroll
            for (int nt = 0; nt < 2; ++nt)
                B3[nt] = *(const f16x8*)(p3 + nt * 512);
        }

        // ---- biases indexed by n = nt*16+lq*4+j -> float4 loads ----
        float4 b1v[4], b2v[2];
        #pragma unroll
        for (int nt = 0; nt < 4; ++nt) b1v[nt] = *(const float4*)(b1 + f * 64 + nt * 16 + lq * 4);
        #pragma unroll
        for (int nt = 0; nt < 2; ++nt) b2v[nt] = *(const float4*)(b2 + f * 32 + nt * 16 + lq * 4);
        float vmt[2], msr[2];
        #pragma unroll
        for (int mt = 0; mt < 2; ++mt) {
            vmt[mt] = tv[wave * 32 + mt * 16 + lr][fi];
            msr[mt] = tm[wave * 32 + mt * 16 + lr][fi];
        }

        // ---- layer 0: build H0 fragments in registers (w0 = +/- g0) ----
        f16x8 A0[2][2];
        #pragma unroll
        for (int ks = 0; ks < 2; ++ks) {
            float w0v[8], b0v[8];
            *(float4*)&w0v[0] = *(const float4*)(w0 + f * 64 + ks * 32 + lq * 8);
            *(float4*)&w0v[4] = *(const float4*)(w0 + f * 64 + ks * 32 + lq * 8 + 4);
            *(float4*)&b0v[0] = *(const float4*)(b0 + f * 64 + ks * 32 + lq * 8);
            *(float4*)&b0v[4] = *(const float4*)(b0 + f * 64 + ks * 32 + lq * 8 + 4);
            #pragma unroll
            for (int mt = 0; mt < 2; ++mt) {
                float h[8];
                #pragma unroll
                for (int i = 0; i < 8; ++i)
                    h[i] = fmaxf(fmaf(vmt[mt], w0v[i], b0v[i]), 0.f);
                union { fp16x2 h2[4]; f16x8 h8; } u;
                u.h2[0] = __builtin_amdgcn_cvt_pkrtz(h[0], h[1]);
                u.h2[1] = __builtin_amdgcn_cvt_pkrtz(h[2], h[3]);
                u.h2[2] = __builtin_amdgcn_cvt_pkrtz(h[4], h[5]);
                u.h2[3] = __builtin_amdgcn_cvt_pkrtz(h[6], h[7]);
                A0[mt][ks] = u.h8;
            }
        }

        // ---- layer 1 SWAPPED: D^T[n][row] = mfma(W1, H0) ----
        f32x4 acc1[4][2];   // [nt][mt]
        #pragma unroll
        for (int nt = 0; nt < 4; ++nt)
            #pragma unroll
            for (int mt = 0; mt < 2; ++mt) acc1[nt][mt] = (f32x4){0.f, 0.f, 0.f, 0.f};
        #pragma unroll
        for (int ks = 0; ks < 2; ++ks)
            #pragma unroll
            for (int nt = 0; nt < 4; ++nt)
                #pragma unroll
                for (int mt = 0; mt < 2; ++mt)
                    acc1[nt][mt] = __builtin_amdgcn_mfma_f32_16x16x32_f16(B1[ks][nt], A0[mt][ks], acc1[nt][mt], 0, 0, 0);
        // relu+bias -> packed b64 -> swizzled LDS  h1[row][n], pitch 128B
        #pragma unroll
        for (int mt = 0; mt < 2; ++mt) {
            int row = mt * 16 + lr;
            int swz = (row & 7) << 4;
            #pragma unroll
            for (int nt = 0; nt < 4; ++nt) {
                int byte = ((row << 7) + nt * 32 + lq * 8) ^ swz;
                *(f16x4*)(h1b + byte) = pack4(
                    fmaxf(acc1[nt][mt][0] + b1v[nt].x, 0.f),
                    fmaxf(acc1[nt][mt][1] + b1v[nt].y, 0.f),
                    fmaxf(acc1[nt][mt][2] + b1v[nt].z, 0.f),
                    fmaxf(acc1[nt][mt][3] + b1v[nt].w, 0.f));
            }
        }

        // ---- layer 2 SWAPPED: read H1 frags, D^T = mfma(W2, H1) ----
        f16x8 A1[2][2];
        #pragma unroll
        for (int mt = 0; mt < 2; ++mt)
            #pragma unroll
            for (int ks = 0; ks < 2; ++ks) {
                int row = mt * 16 + lr;
                int byte = ((row << 7) + ((ks * 4 + lq) << 4)) ^ ((row & 7) << 4);
                A1[mt][ks] = *(const f16x8*)(h1b + byte);
            }
        f32x4 acc2[2][2];   // [nt][mt]
        #pragma unroll
        for (int nt = 0; nt < 2; ++nt)
            #pragma unroll
            for (int mt = 0; mt < 2; ++mt) acc2[nt][mt] = (f32x4){0.f, 0.f, 0.f, 0.f};
        #pragma unroll
        for (int ks = 0; ks < 2; ++ks)
            #pragma unroll
            for (int nt = 0; nt < 2; ++nt)
                #pragma unroll
                for (int mt = 0; mt < 2; ++mt)
                    acc2[nt][mt] = __builtin_amdgcn_mfma_f32_16x16x32_f16(B2[ks][nt], A1[mt][ks], acc2[nt][mt], 0, 0, 0);
        #pragma unroll
        for (int mt = 0; mt < 2; ++mt) {
            int row = mt * 16 + lr;
            int swz = (row & 7) << 4;
            #pragma unroll
            for (int nt = 0; nt < 2; ++nt) {
                int byte = ((row << 7) + nt * 32 + lq * 8) ^ swz;
                *(f16x4*)(h2b + byte) = pack4(
                    fmaxf(acc2[nt][mt][0] + b2v[nt].x, 0.f),
                    fmaxf(acc2[nt][mt][1] + b2v[nt].y, 0.f),
                    fmaxf(acc2[nt][mt][2] + b2v[nt].z, 0.f),
                    fmaxf(acc2[nt][mt][3] + b2v[nt].w, 0.f));
            }
        }

        // ---- layer 3 SWAPPED (verified R4): D^T = mfma(W3, H2) ----
        f16x8 A2[2];
        #pragma unroll
        for (int mt = 0; mt < 2; ++mt) {
            int row = mt * 16 + lr;
            int byte = ((row << 7) + (lq << 4)) ^ ((row & 7) << 4);
            A2[mt] = *(const f16x8*)(h2b + byte);
        }
        f32x4 accT[2][2];
        #pragma unroll
        for (int nt = 0; nt < 2; ++nt)
            #pragma unroll
            for (int mt = 0; mt < 2; ++mt) accT[nt][mt] = (f32x4){0.f, 0.f, 0.f, 0.f};
        #pragma unroll
        for (int nt = 0; nt < 2; ++nt)
            #pragma unroll
            for (int mt = 0; mt < 2; ++mt)
                accT[nt][mt] = __builtin_amdgcn_mfma_f32_16x16x32_f16(B3[nt], A2[mt], accT[nt][mt], 0, 0, 0);

        // ---- epilogue: mask (per-lane row), missing-emb (contiguous o), float4 store ----
        const bool hasemb = (f < 16);
        float4 e[2] = {{0, 0, 0, 0}, {0, 0, 0, 0}};
        if (hasemb) {
            #pragma unroll
            for (int nt = 0; nt < 2; ++nt)
                e[nt] = *(const float4*)(memb + (8 + f) * 32 + nt * 16 + lq * 4);
        }
        #pragma unroll
        for (int mt = 0; mt < 2; ++mt) {
            const int row = rowbase + mt * 16 + lr;
            const float m = msr[mt];
            const float keep = 1.f - m;
            float* dst = feat + (size_t)row * 3072 + f * 32 + lq * 4;
            #pragma unroll
            for (int nt = 0; nt < 2; ++nt) {
                float4 v;
                v.x = accT[nt][mt][0] * keep;
                v.y = accT[nt][mt][1] * keep;
                v.z = accT[nt][mt][2] * keep;
                v.w = accT[nt][mt][3] * keep;
                if (hasemb) {
                    v.x = fmaf(e[nt].x, m, v.x);
                    v.y = fmaf(e[nt].y, m, v.y);
                    v.z = fmaf(e[nt].z, m, v.z);
                    v.w = fmaf(e[nt].w, m, v.w);
                }
                *(float4*)(dst + nt * 16) = v;
                lacc[mt][nt][0] += v.x;
                lacc[mt][nt][1] += v.y;
                lacc[mt][nt][2] += v.z;
                lacc[mt][nt][3] += v.w;
            }
        }
    }

    // ---- partial-plane store (float4, no atomics) ----
    if (part) {
        float* pp = part + (size_t)blockIdx.y * LOGN;
        #pragma unroll
        for (int mt = 0; mt < 2; ++mt) {
            const int row = rowbase + mt * 16 + lr;
            #pragma unroll
            for (int nt = 0; nt < 2; ++nt) {
                float4 v;
                v.x = lacc[mt][nt][0]; v.y = lacc[mt][nt][1];
                v.z = lacc[mt][nt][2]; v.w = lacc[mt][nt][3];
                *(float4*)(pp + (size_t)row * 32 + nt * 16 + lq * 4) = v;
            }
        }
    }
}

// ---------------- categorical features + final logits (fused, vectorized) ----------------
__global__ __launch_bounds__(256)
void nam_cat_reduce(const float* __restrict__ tab, const float* __restrict__ cat_linear,
                    const float* __restrict__ memb, const float* __restrict__ bias,
                    const float* __restrict__ part, float* __restrict__ feat,
                    float* __restrict__ logits) {
    int t = blockIdx.x * 256 + threadIdx.x;   // 65536
    int o4 = (t & 7) * 4;
    int b = t >> 3;
    const float4* tb4 = (const float4*)(tab + (size_t)b * 192);
    float4 s = *(const float4*)(bias + o4);
    if (part) {
        #pragma unroll
        for (int g = 0; g < 8; ++g) {
            float4 p = *(const float4*)(part + (size_t)g * LOGN + (size_t)b * 32 + o4);
            s.x += p.x; s.y += p.y; s.z += p.z; s.w += p.w;
        }
    }
    float* fb = feat + (size_t)b * 3072 + 64 * 32 + o4;
    #pragma unroll
    for (int q = 0; q < 8; ++q) {
        float4 v4 = tb4[16 + q];     // values cols 64+4q..
        float4 m4 = tb4[40 + q];     // missing cols 160+4q..
        float vv[4] = {v4.x, v4.y, v4.z, v4.w};
        float mm[4] = {m4.x, m4.y, m4.z, m4.w};
        #pragma unroll
        for (int e = 0; e < 4; ++e) {
            int fc = q * 4 + e;
            float vk = vv[e] * (1.f - mm[e]);
            float4 cl4 = *(const float4*)(cat_linear + fc * 32 + o4);
            float4 r;
            r.x = cl4.x * vk; r.y = cl4.y * vk; r.z = cl4.z * vk; r.w = cl4.w * vk;
            if (fc < 8) {
                float4 mb4 = *(const float4*)(memb + fc * 32 + o4);
                r.x = fmaf(mb4.x, mm[e], r.x);
                r.y = fmaf(mb4.y, mm[e], r.y);
                r.z = fmaf(mb4.z, mm[e], r.z);
                r.w = fmaf(mb4.w, mm[e], r.w);
            }
            *(float4*)(fb + fc * 32) = r;
            s.x += r.x; s.y += r.y; s.z += r.z; s.w += r.w;
        }
    }
    if (part) *(float4*)(logits + (size_t)b * 32 + o4) = s;
}

// ---------------- fallback logits (if ws too small for partials) ----------------
__global__ __launch_bounds__(256)
void nam_logits(const float* __restrict__ feat, const float* __restrict__ bias,
                float* __restrict__ logits) {
    int t = blockIdx.x * 256 + threadIdx.x;   // 65536
    int o4 = (t & 7) * 4;
    int b = t >> 3;
    float4 s = *(const float4*)(bias + o4);
    const float* fp = feat + (size_t)b * 3072 + o4;
    #pragma unroll 8
    for (int f = 0; f < 96; ++f) {
        float4 p = *(const float4*)(fp + f * 32);
        s.x += p.x; s.y += p.y; s.z += p.z; s.w += p.w;
    }
    *(float4*)(logits + (size_t)b * 32 + o4) = s;
}

extern "C" void kernel_launch(void* const* d_in, const int* in_sizes, int n_in,
                              void* d_out, int out_size, void* d_ws, size_t ws_size,
                              hipStream_t stream) {
    const float* tab        = (const float*)d_in[0];
    const float* v0         = (const float*)d_in[1];
    const float* g0         = (const float*)d_in[2];
    const float* b0         = (const float*)d_in[3];
    const float* v1         = (const float*)d_in[4];
    const float* g1         = (const float*)d_in[5];
    const float* b1         = (const float*)d_in[6];
    const float* v2         = (const float*)d_in[7];
    const float* g2         = (const float*)d_in[8];
    const float* b2         = (const float*)d_in[9];
    const float* v3         = (const float*)d_in[10];
    const float* g3         = (const float*)d_in[11];
    const float* cat_linear = (const float*)d_in[12];
    const float* memb       = (const float*)d_in[13];
    const float* bias       = (const float*)d_in[14];

    float* out    = (float*)d_out;
    float* logits = out;                 // [8192][32]
    float* feat   = out + LOGN;          // [8192][96][32]

    float* w0   = (float*)((char*)d_ws + OFF_W0);
    f16*   b1f  = (f16*)((char*)d_ws + OFF_B1);
    f16*   b2f  = (f16*)((char*)d_ws + OFF_B2);
    f16*   b3f  = (f16*)((char*)d_ws + OFF_B3);
    float* part = (float*)((char*)d_ws + OFF_PART);
    const bool use_part = ws_size >= WS_NEED;
    float* partp = use_part ? part : nullptr;

    prep_all<<<1808, 256, 0, stream>>>(v0, g0, v1, g1, v2, g2, v3, g3, w0, b1f, b2f, b3f);

    dim3 gr(64, 8);
    nam_real_mfma<<<gr, 256, 0, stream>>>(tab, w0, b1f, b2f, b3f, b0, b1, b2, memb, feat, partp);

    nam_cat_reduce<<<256, 256, 0, stream>>>(tab, cat_linear, memb, bias, partp, feat, logits);

    if (!use_part)
        nam_logits<<<256, 256, 0, stream>>>(feat, bias, logits);
}